// Round 18
// baseline (136.547 us; speedup 1.0000x reference)
//
#include <hip/hip_runtime.h>
#include <stdint.h>

typedef __attribute__((ext_vector_type(8))) short bf16x8;
typedef __attribute__((ext_vector_type(4))) short s16x4;
typedef __attribute__((ext_vector_type(4))) float f32x4;

__device__ __forceinline__ ushort f2bf(float f) {
  union { float f; uint32_t u; } c; c.f = f;
  uint32_t r = (c.u + 0x7fffu + ((c.u >> 16) & 1u)) >> 16;
  return (ushort)r;
}

__device__ __forceinline__ float bf2f(ushort u) {
  return __uint_as_float((uint32_t)u << 16);
}

__device__ __forceinline__ void gload16(const void* g, void* l) {
  __builtin_amdgcn_global_load_lds(
      (const __attribute__((address_space(1))) void*)g,
      (__attribute__((address_space(3))) void*)l, 16, 0, 0);
}

__device__ __forceinline__ unsigned lds_addr(const void* p) {
  return (unsigned)(uintptr_t)(__attribute__((address_space(3))) const char*)p;
}

__device__ __forceinline__ uint32_t cvtpk(float lo, float hi) {
  uint32_t d;
  asm("v_cvt_pk_bf16_f32 %0, %1, %2" : "=v"(d) : "v"(lo), "v"(hi));
  return d;
}

// ---------------- fused prep: LN(q) + cast k,v + cast 4 weights ----------------
__global__ __launch_bounds__(256) void prep_kernel(
    const float* __restrict__ q, const float* __restrict__ k,
    const float* __restrict__ v, const float* __restrict__ w_q,
    const float* __restrict__ w_k, const float* __restrict__ w_v,
    const float* __restrict__ w_o, const float* __restrict__ ln_g,
    const float* __restrict__ ln_b,
    ushort* __restrict__ qn, ushort* __restrict__ kb, ushort* __restrict__ vb,
    ushort* __restrict__ wqb, ushort* __restrict__ wkb,
    ushort* __restrict__ wvb, ushort* __restrict__ wob) {
  const int bid = blockIdx.x;
  const int t = threadIdx.x;
  if (bid < 4096) {
    const int row = bid;
    const float4 val = ((const float4*)(q + (size_t)row * 1024))[t];
    float s  = val.x + val.y + val.z + val.w;
    float s2 = val.x*val.x + val.y*val.y + val.z*val.z + val.w*val.w;
    #pragma unroll
    for (int off = 1; off < 64; off <<= 1) {
      s  += __shfl_xor(s,  off);
      s2 += __shfl_xor(s2, off);
    }
    __shared__ float red[8];
    const int wave = t >> 6, lane = t & 63;
    if (lane == 0) { red[wave*2] = s; red[wave*2+1] = s2; }
    __syncthreads();
    s  = red[0] + red[2] + red[4] + red[6];
    s2 = red[1] + red[3] + red[5] + red[7];
    const float mu = s * (1.0f/1024.0f);
    const float var = s2 * (1.0f/1024.0f) - mu*mu;
    const float rs = rsqrtf(var + 1e-6f);
    const float4 gg = ((const float4*)ln_g)[t];
    const float4 bb = ((const float4*)ln_b)[t];
    ushort4 o;
    o.x = f2bf((val.x - mu) * rs * gg.x + bb.x);
    o.y = f2bf((val.y - mu) * rs * gg.y + bb.y);
    o.z = f2bf((val.z - mu) * rs * gg.z + bb.z);
    o.w = f2bf((val.w - mu) * rs * gg.w + bb.w);
    ((ushort4*)(qn + (size_t)row * 1024))[t] = o;
    return;
  }
  const float* in; ushort* out; int i;
  if (bid < 12288) {
    const int idx = bid - 4096;
    const bool isv = idx >= 4096;
    in  = isv ? v : k;
    out = isv ? vb : kb;
    i = (idx & 4095) * 256 + t;
  } else {
    const int idx = bid - 12288;
    const int w = idx >> 10;
    in  = w == 0 ? w_q : (w == 1 ? w_k : (w == 2 ? w_v : w_o));
    out = w == 0 ? wqb : (w == 1 ? wkb : (w == 2 ? wvb : wob));
    i = (idx & 1023) * 256 + t;
  }
  const float4 val = ((const float4*)in)[i];
  ushort4 o;
  o.x = f2bf(val.x); o.y = f2bf(val.y); o.z = f2bf(val.z); o.w = f2bf(val.w);
  ((ushort4*)out)[i] = o;
}

// ---------------- mask tile flags (64x64 granularity) ----------------
__global__ __launch_bounds__(256) void mask_flags(
    const int* __restrict__ mask, int* __restrict__ flags) {
  const int qt = blockIdx.y, kt = blockIdx.x;
  const int t = threadIdx.x;
  const int* p = mask + (size_t)(qt * 64 + (t >> 2)) * 2048 + kt * 64 + (t & 3) * 16;
  int ok = 1;
  #pragma unroll
  for (int i = 0; i < 4; i++) {
    const int4 m = ((const int4*)p)[i];
    ok &= (m.x != 0) & (m.y != 0) & (m.z != 0) & (m.w != 0);
  }
  __shared__ int sok;
  if (t == 0) sok = 1;
  __syncthreads();
  if (!ok) atomicAnd(&sok, 0);
  __syncthreads();
  if (t == 0) flags[qt * 32 + kt] = sok;
}

// ---------------- QKV GEMM: 3 LDS buffers, unroll-by-3 static addressing -------
__global__ __launch_bounds__(256, 3) void gemm3(
    const ushort* __restrict__ A0, const ushort* __restrict__ W0, ushort* __restrict__ C0,
    const ushort* __restrict__ A1, const ushort* __restrict__ W1, ushort* __restrict__ C1,
    const ushort* __restrict__ A2, const ushort* __restrict__ W2, ushort* __restrict__ C2,
    float qscale) {
  __shared__ ushort As[3][4096];
  __shared__ ushort Bs[3][4096];
  const int t = threadIdx.x, lane = t & 63, wave = t >> 6;
  const int wr = wave >> 1, wc = wave & 1;
  const int lr = lane & 15, lg = lane >> 4;
  const int lin = blockIdx.x;
  const int swz = (lin & 7) * 96 + (lin >> 3);     // bijective: 768 = 8*96
  const int brow = ((swz >> 3) & 31) * 128, bcol = (swz & 7) * 128;
  const int z = swz >> 8;
  const ushort* A = z == 0 ? A0 : (z == 1 ? A1 : A2);
  const ushort* W = z == 0 ? W0 : (z == 1 ? W1 : W2);
  ushort*      C = z == 0 ? C0 : (z == 1 ? C1 : C2);
  const float sc = (z == 0) ? qscale : 1.0f;
  f32x4 acc[4][4] = {};
  const int r_ = t >> 2, cx = (t & 3) ^ ((r_ >> 1) & 3);   // source chunk XOR
  const ushort* gA  = A + (size_t)(brow + r_) * 1024 + cx * 8;
  const ushort* gB  = W + (size_t)(bcol + r_) * 1024 + cx * 8;
  const ushort* gA2 = gA + 64 * 1024;
  const ushort* gB2 = gB + 64 * 1024;
  const int woff = wave * 1024;                            // bytes
  char* const la0 = (char*)As[0] + woff;
  char* const la1 = (char*)As[1] + woff;
  char* const la2 = (char*)As[2] + woff;
  char* const lb0 = (char*)Bs[0] + woff;
  char* const lb1 = (char*)Bs[1] + woff;
  char* const lb2 = (char*)Bs[2] + woff;
  const int xA = ((lr >> 1) & 3) * 8;                      // read-side XOR (ushorts)

#define G_ISSUE_U(LA, LB, OFF) { \
    gload16(gA  + (OFF), (LA));        gload16(gA2 + (OFF), (LA) + 4096); \
    gload16(gB  + (OFF), (LB));        gload16(gB2 + (OFF), (LB) + 4096); }

#define G_COMPUTE_U(BI) { \
    const ushort* as_ = As[BI]; \
    const ushort* bs_ = Bs[BI]; \
    bf16x8 af[4], bfr[4]; \
    _Pragma("unroll") for (int i = 0; i < 4; i++) \
      af[i]  = *(const bf16x8*)&as_[(wr*64 + i*16 + lr) * 32 + ((lg*8) ^ xA)]; \
    _Pragma("unroll") for (int i = 0; i < 4; i++) \
      bfr[i] = *(const bf16x8*)&bs_[(wc*64 + i*16 + lr) * 32 + ((lg*8) ^ xA)]; \
    _Pragma("unroll") for (int mi = 0; mi < 4; mi++) \
      _Pragma("unroll") for (int ni = 0; ni < 4; ni++) \
        acc[mi][ni] = __builtin_amdgcn_mfma_f32_16x16x32_bf16(af[mi], bfr[ni], acc[mi][ni], 0, 0, 0); }

  G_ISSUE_U(la0, lb0, 0);
  G_ISSUE_U(la1, lb1, 32);
  for (int k = 0; k < 10; ++k) {
    asm volatile("s_waitcnt vmcnt(4)" ::: "memory");
    __builtin_amdgcn_s_barrier();
    G_ISSUE_U(la2, lb2, 64);
    G_COMPUTE_U(0);
    asm volatile("s_waitcnt vmcnt(4)" ::: "memory");
    __builtin_amdgcn_s_barrier();
    G_ISSUE_U(la0, lb0, 96);
    G_COMPUTE_U(1);
    asm volatile("s_waitcnt vmcnt(4)" ::: "memory");
    __builtin_amdgcn_s_barrier();
    G_ISSUE_U(la1, lb1, 128);
    G_COMPUTE_U(2);
    gA += 96; gA2 += 96; gB += 96; gB2 += 96;
  }
  asm volatile("s_waitcnt vmcnt(4)" ::: "memory");
  __builtin_amdgcn_s_barrier();
  G_COMPUTE_U(0);
  asm volatile("s_waitcnt vmcnt(0)" ::: "memory");
  __builtin_amdgcn_s_barrier();
  G_COMPUTE_U(1);
#undef G_ISSUE_U
#undef G_COMPUTE_U

  #pragma unroll
  for (int mi = 0; mi < 4; mi++) {
    #pragma unroll
    for (int ni = 0; ni < 4; ni++) {
      #pragma unroll
      for (int r = 0; r < 4; r++) {
        const size_t row = brow + wr*64 + mi*16 + lg*4 + r;
        const size_t col = bcol + wc*64 + ni*16 + lr;
        C[row * 1024 + col] = f2bf(acc[mi][ni][r] * sc);
      }
    }
  }
}

// ---------------- Final GEMM: BM=64, XCD+T2 swizzles, fused residual -----------
__global__ __launch_bounds__(256) void gemm_bm64(
    const ushort* __restrict__ A, const ushort* __restrict__ W,
    float* __restrict__ Cf, const float* __restrict__ resid) {
  __shared__ ushort As[4][2048];
  __shared__ ushort Bs[4][4096];
  const int t = threadIdx.x, lane = t & 63, wave = t >> 6;
  const int wr = wave >> 1, wc = wave & 1;
  const int lr = lane & 15, lg = lane >> 4;
  const int lin = blockIdx.x;
  const int swz = (lin & 7) * 64 + (lin >> 3);     // bijective: 512 = 8*64
  const int brow = (swz >> 3) * 64, bcol = (swz & 7) * 128;
  f32x4 acc[2][4] = {};
  const int r_ = t >> 2, cx = (t & 3) ^ ((r_ >> 1) & 3);
  const ushort* gA = A + (size_t)(brow + r_) * 1024 + cx * 8;
  const ushort* gB = W + (size_t)(bcol + r_) * 1024 + cx * 8;
  const int woff = wave * 1024;
  const int xA = ((lr >> 1) & 3) * 8;

#define G_ISSUE(S) { \
    char* la = (char*)As + ((S) & 3) * 4096 + woff; \
    char* lb = (char*)Bs + ((S) & 3) * 8192 + woff; \
    const ushort* ap_ = gA + (S) * 32; \
    const ushort* bp_ = gB + (S) * 32; \
    gload16(ap_, la); \
    gload16(bp_, lb); gload16(bp_ + 64 * 1024, lb + 4096); }

#define G_COMPUTE(S) { \
    const ushort* as_ = As[(S) & 3]; \
    const ushort* bs_ = Bs[(S) & 3]; \
    bf16x8 af[2], bfr[4]; \
    _Pragma("unroll") for (int i = 0; i < 2; i++) \
      af[i]  = *(const bf16x8*)&as_[(wr*32 + i*16 + lr) * 32 + ((lg*8) ^ xA)]; \
    _Pragma("unroll") for (int i = 0; i < 4; i++) \
      bfr[i] = *(const bf16x8*)&bs_[(wc*64 + i*16 + lr) * 32 + ((lg*8) ^ xA)]; \
    _Pragma("unroll") for (int mi = 0; mi < 2; mi++) \
      _Pragma("unroll") for (int ni = 0; ni < 4; ni++) \
        acc[mi][ni] = __builtin_amdgcn_mfma_f32_16x16x32_bf16(af[mi], bfr[ni], acc[mi][ni], 0, 0, 0); }

  G_ISSUE(0); G_ISSUE(1); G_ISSUE(2);
  for (int s = 0; s < 30; ++s) {
    asm volatile("s_waitcnt vmcnt(6)" ::: "memory");
    __builtin_amdgcn_s_barrier();
    if (s < 29) G_ISSUE(s + 3);
    G_COMPUTE(s);
  }
  asm volatile("s_waitcnt vmcnt(3)" ::: "memory");
  __builtin_amdgcn_s_barrier();
  G_COMPUTE(30);
  asm volatile("s_waitcnt vmcnt(0)" ::: "memory");
  __builtin_amdgcn_s_barrier();
  G_COMPUTE(31);
#undef G_ISSUE
#undef G_COMPUTE

  #pragma unroll
  for (int mi = 0; mi < 2; mi++) {
    #pragma unroll
    for (int ni = 0; ni < 4; ni++) {
      #pragma unroll
      for (int r = 0; r < 4; r++) {
        const size_t row = brow + wr*32 + mi*16 + lg*4 + r;
        const size_t col = bcol + wc*64 + ni*16 + lr;
        Cf[row * 1024 + col] = acc[mi][ni][r] + resid[row * 1024 + col];
      }
    }
  }
}

// ---------------- Flash attention: 32q/wave + KV-split x2, 32KB LDS ------------
// Grid 512 = (8qb x 2split, 16h, 2b) -> 2 blocks/CU; VGPR ~90 -> 4 waves/SIMD.
// R17-proven body (shared K-frags/V-frags feed both q-tiles); single-tile K/V
// double buffers; m=0 softmax -> split-combine (P0+P1)/(l0+l1) is exact.
__global__ __launch_bounds__(512) void flash_attn(
    const ushort* __restrict__ Qp, const ushort* __restrict__ Kp,
    const ushort* __restrict__ Vp, const int* __restrict__ mask,
    const int* __restrict__ tflags,
    ushort* __restrict__ P0, ushort* __restrict__ P1,
    float* __restrict__ l0, float* __restrict__ l1) {
  const int L = 2048;
  const int lin = blockIdx.x;
  const int swzb = (lin & 7) * 64 + (lin >> 3);    // bijective: 512 = 8*64
  const int split = swzb & 1, qb = (swzb >> 1) & 7;
  const int h = (swzb >> 4) & 15, b = swzb >> 8;
  const int t = threadIdx.x, lane = t & 63, wave = t >> 6;   // wave 0..7
  const int l15 = lane & 15, hg = lane >> 4;                 // hg 0..3
  __shared__ ushort Ks[2][4096];   // single-tile double buffer: 8KB each
  __shared__ ushort Vs[2][4096];
  const size_t base = (size_t)b * L * 1024 + h * 64;
  const int qw0 = qb * 256 + wave * 32;            // this wave's 32 q-rows
  const int T0 = split * 16;                       // 16 kv-tiles per split

  // Q B-frags: qf[qt][kc], lane holds q-col = l15, d = kc*32 + hg*8 + j
  bf16x8 qf[2][2];
  #pragma unroll
  for (int qt = 0; qt < 2; qt++)
    #pragma unroll
    for (int kc = 0; kc < 2; kc++)
      qf[qt][kc] = *(const bf16x8*)(Qp + base +
                     (size_t)(qw0 + qt*16 + l15) * 1024 + kc*32 + hg*8);

  f32x4 accO[2][4] = {};           // [qt][dblk]
  f32x4 accL[2] = {};
  const bf16x8 onef = {16256, 16256, 16256, 16256, 16256, 16256, 16256, 16256};

  // K staging: row r5 = t>>3, source chunk (t&7)^(r5&7) -> XOR-swizzled
  const int r5 = t >> 3;
  const ushort* gK = Kp + base + (size_t)r5 * 1024 + ((t & 7) ^ (r5 & 7)) * 8;
  // V staging: subtile order
  const int vkv = (t >> 5) * 4 + ((t & 7) >> 1);
  const int vd  = ((t >> 3) & 3) * 16 + (t & 1) * 8;
  const ushort* gV = Vp + base + (size_t)vkv * 1024 + vd;

  const unsigned vbase = lds_addr((const char*)Vs) + hg * 1024 + l15 * 8;

#define STAGE(T, BUF) { \
    gload16(gK + (size_t)(T) * 65536, (char*)Ks[BUF] + wave * 1024); \
    gload16(gV + (size_t)(T) * 65536, (char*)Vs[BUF] + wave * 1024); }

#define TRREAD(VLO, VHI, VA, C) { \
    _Pragma("unroll") for (int dblk = 0; dblk < 4; dblk++) \
      asm volatile("ds_read_b64_tr_b16 %0, %2 offset:%3\n\t" \
                   "ds_read_b64_tr_b16 %1, %2 offset:%4" \
                   : "=v"(VLO[dblk]), "=v"(VHI[dblk]) \
                   : "v"(VA), "i"((C)*4096 + dblk*128), "i"((C)*4096 + dblk*128 + 512) \
                   : "memory"); }

  STAGE(T0, 0);
  const int flagBase = (qb * 4 + (wave >> 1)) * 32;

  for (int s = 0; s < 16; ++s) {
    asm volatile("s_waitcnt vmcnt(0)" ::: "memory");
    __builtin_amdgcn_s_barrier();
    if (s + 1 < 16) { STAGE(T0 + s + 1, (s + 1) & 1); }

    const int kvt = T0 + s;
    const char* KsB = (const char*)Ks[s & 1];
    const unsigned va = vbase + (s & 1) * 8192;

    // ---- S^T = K Q^T : K-frags read ONCE, feed both q-tiles
    f32x4 sc[2][4] = {};
    const int rx16 = (l15 & 7) << 4;
    __builtin_amdgcn_s_setprio(1);
    #pragma unroll
    for (int kc = 0; kc < 2; kc++) {
      const int cb = (kc*64 + hg*16) ^ rx16;
      const bf16x8 k0 = *(const bf16x8*)(KsB + (     l15) * 128 + cb);
      const bf16x8 k1 = *(const bf16x8*)(KsB + (16 + l15) * 128 + cb);
      const bf16x8 k2 = *(const bf16x8*)(KsB + (32 + l15) * 128 + cb);
      const bf16x8 k3 = *(const bf16x8*)(KsB + (48 + l15) * 128 + cb);
      #pragma unroll
      for (int qt = 0; qt < 2; qt++) {
        sc[qt][0] = __builtin_amdgcn_mfma_f32_16x16x32_bf16(k0, qf[qt][kc], sc[qt][0], 0, 0, 0);
        sc[qt][1] = __builtin_amdgcn_mfma_f32_16x16x32_bf16(k1, qf[qt][kc], sc[qt][1], 0, 0, 0);
        sc[qt][2] = __builtin_amdgcn_mfma_f32_16x16x32_bf16(k2, qf[qt][kc], sc[qt][2], 0, 0, 0);
        sc[qt][3] = __builtin_amdgcn_mfma_f32_16x16x32_bf16(k3, qf[qt][kc], sc[qt][3], 0, 0, 0);
      }
    }
    __builtin_amdgcn_s_setprio(0);

    // ---- tr-reads chunk 0 (kv 0-31 of this tile)
    s16x4 vlo[4], vhi[4];
    TRREAD(vlo, vhi, va, 0);

    // ---- mask (rare path)
    if (tflags[flagBase + kvt] == 0) {
      #pragma unroll
      for (int qt = 0; qt < 2; qt++) {
        const size_t mrow = (size_t)(qw0 + qt*16 + l15) * L + kvt * 64;
        #pragma unroll
        for (int r = 0; r < 4; ++r) {
          const int kvr = hg*4 + r;
          if (mask[mrow + kvr] == 0)      sc[qt][0][r] = -1e9f;
          if (mask[mrow + 16 + kvr] == 0) sc[qt][1][r] = -1e9f;
          if (mask[mrow + 32 + kvr] == 0) sc[qt][2][r] = -1e9f;
          if (mask[mrow + 48 + kvr] == 0) sc[qt][3][r] = -1e9f;
        }
      }
    }

    // ---- p = exp2(s)
    #pragma unroll
    for (int qt = 0; qt < 2; qt++)
      #pragma unroll
      for (int ni = 0; ni < 4; ++ni)
        #pragma unroll
        for (int r = 0; r < 4; ++r)
          sc[qt][ni][r] = __builtin_amdgcn_exp2f(sc[qt][ni][r]);

    // ---- repack P into A-frags (per qt, per 32-kv chunk)
    union U8 { uint32_t u[4]; bf16x8 v; };
    bf16x8 pa[2][2];
    #pragma unroll
    for (int qt = 0; qt < 2; qt++) {
      #pragma unroll
      for (int c = 0; c < 2; ++c) {
        const f32x4& ta = sc[qt][2*c];
        const f32x4& tb = sc[qt][2*c + 1];
        uint32_t A = cvtpk(ta[0], ta[1]), B = cvtpk(ta[2], ta[3]);
        uint32_t C = cvtpk(tb[0], tb[1]), D = cvtpk(tb[2], tb[3]);
        asm("v_permlane32_swap_b32 %0, %1" : "+v"(A), "+v"(C));
        asm("v_permlane16_swap_b32 %0, %1" : "+v"(A), "+v"(C));
        asm("v_permlane32_swap_b32 %0, %1" : "+v"(B), "+v"(D));
        asm("v_permlane16_swap_b32 %0, %1" : "+v"(B), "+v"(D));
        U8 f; f.u[0] = A; f.u[1] = B; f.u[2] = C; f.u[3] = D;
        pa[qt][c] = f.v;
      }
    }

    // ---- PV chunk 0 + l
    asm volatile("s_waitcnt lgkmcnt(0)" ::: "memory");
    __builtin_amdgcn_sched_barrier(0);
    __builtin_amdgcn_s_setprio(1);
    #pragma unroll
    for (int dblk = 0; dblk < 4; dblk++) {
      const bf16x8 bv = __builtin_shufflevector(vlo[dblk], vhi[dblk],
                                                0, 1, 2, 3, 4, 5, 6, 7);
      accO[0][dblk] = __builtin_amdgcn_mfma_f32_16x16x32_bf16(pa[0][0], bv, accO[0][dblk], 0, 0, 0);
      accO[1][dblk] = __builtin_amdgcn_mfma_f32_16x16x32_bf16(pa[1][0], bv, accO[1][dblk], 0, 0, 0);
    }
    accL[0] = __builtin_amdgcn_mfma_f32_16x16x32_bf16(pa[0][0], onef, accL[0], 0, 0, 0);
    accL[1] = __builtin_amdgcn_mfma_f32_16x16x32_bf16(pa[1][0], onef, accL[1], 0, 0, 0);
    __builtin_amdgcn_s_setprio(0);

    // ---- tr-reads chunk 1, PV chunk 1 + l
    TRREAD(vlo, vhi, va, 1);
    asm volatile("s_waitcnt lgkmcnt(0)" ::: "memory");
    __builtin_amdgcn_sched_barrier(0);
    __builtin_amdgcn_s_setprio(1);
    #pragma unroll
    for (int dblk = 0; dblk < 4; dblk++) {
      const bf16x8 bv = __builtin_shufflevector(vlo[dblk], vhi[dblk],
                                                0, 1, 2, 3, 4, 5, 6, 7);
      accO[0][dblk] = __builtin_amdgcn_mfma_f32_16x16x32_bf16(pa[0][1], bv, accO[0][dblk], 0, 0, 0);
      accO[1][dblk] = __builtin_amdgcn_mfma_f32_16x16x32_bf16(pa[1][1], bv, accO[1][dblk], 0, 0, 0);
    }
    accL[0] = __builtin_amdgcn_mfma_f32_16x16x32_bf16(pa[0][1], onef, accL[0], 0, 0, 0);
    accL[1] = __builtin_amdgcn_mfma_f32_16x16x32_bf16(pa[1][1], onef, accL[1], 0, 0, 0);
    __builtin_amdgcn_s_setprio(0);
  }

  // ---- epilogue: write UNNORMALIZED partial O + partial l
  ushort* Pout = split ? P1 : P0;
  float*  lout = split ? l1 : l0;
  #pragma unroll
  for (int qt = 0; qt < 2; qt++) {
    #pragma unroll
    for (int r = 0; r < 4; ++r) {
      const size_t row = (size_t)b * L + qw0 + qt*16 + hg*4 + r;
      #pragma unroll
      for (int dblk = 0; dblk < 4; dblk++)
        Pout[row * 1024 + h*64 + dblk*16 + l15] = f2bf(accO[qt][dblk][r]);
      if (l15 == 0) lout[row * 16 + h] = accL[qt][r];
    }
  }
#undef STAGE
#undef TRREAD
}

// ---------------- combine: AO = (P0 + P1) / (l0 + l1)  (exact under m=0) ------
__global__ __launch_bounds__(256) void combine_kernel(
    const ushort* __restrict__ P0, const ushort* __restrict__ P1,
    const float* __restrict__ l0, const float* __restrict__ l1,
    ushort* __restrict__ AO) {
  const int i = blockIdx.x * 256 + threadIdx.x;   // 8-elem groups, 524288 total
  const int row = i >> 7;
  const int h = (i >> 3) & 15;
  const float inv = 1.0f / (l0[row * 16 + h] + l1[row * 16 + h]);
  const uint4 A = ((const uint4*)P0)[i];
  const uint4 C = ((const uint4*)P1)[i];
  const ushort* ua = (const ushort*)&A;
  const ushort* uc = (const ushort*)&C;
  union { ushort us[8]; uint4 v; } o;
  #pragma unroll
  for (int j = 0; j < 8; j++)
    o.us[j] = f2bf((bf2f(ua[j]) + bf2f(uc[j])) * inv);
  ((uint4*)AO)[i] = o.v;
}

extern "C" void kernel_launch(void* const* d_in, const int* in_sizes, int n_in,
                              void* d_out, int out_size, void* d_ws, size_t ws_size,
                              hipStream_t stream) {
  const float* q    = (const float*)d_in[0];
  const float* k    = (const float*)d_in[1];
  const float* v    = (const float*)d_in[2];
  const int*   mask = (const int*)d_in[3];
  const float* w_q  = (const float*)d_in[4];
  const float* w_k  = (const float*)d_in[5];
  const float* w_v  = (const float*)d_in[6];
  const float* w_o  = (const float*)d_in[7];
  const float* ln_g = (const float*)d_in[8];
  const float* ln_b = (const float*)d_in[9];
  float* out = (float*)d_out;

  char* ws = (char*)d_ws;
  const size_t MB = (size_t)1 << 20;
  ushort* qn  = (ushort*)(ws + 0*MB);    // LN out; reused as P0 after gemm3
  ushort* kb  = (ushort*)(ws + 8*MB);    // k bf16; reused as P1 after gemm3
  ushort* vb  = (ushort*)(ws + 16*MB);   // v bf16; reused for l0/l1/tflags
  ushort* wqb = (ushort*)(ws + 24*MB);
  ushort* wkb = (ushort*)(ws + 26*MB);
  ushort* wvb = (ushort*)(ws + 28*MB);
  ushort* wob = (ushort*)(ws + 30*MB);
  ushort* Qp  = (ushort*)(ws + 32*MB);
  ushort* Kp  = (ushort*)(ws + 40*MB);
  ushort* Vp  = (ushort*)(ws + 48*MB);
  ushort* AO  = (ushort*)(ws + 56*MB);
  ushort* P0  = (ushort*)(ws + 0*MB);
  ushort* P1  = (ushort*)(ws + 8*MB);
  float*  l0  = (float*)(ws + 16*MB);                  // 256 KB
  float*  l1  = (float*)(ws + 16*MB + 256*1024);       // 256 KB
  int* tflags = (int*)(ws + 16*MB + 512*1024);         // 4 KB (vb region, dead)

  const float QSCALE = 0.125f * 1.44269504089f;   // 1/sqrt(64) * log2(e)

  prep_kernel<<<16384, 256, 0, stream>>>(
      q, k, v, w_q, w_k, w_v, w_o, ln_g, ln_b,
      qn, kb, vb, wqb, wkb, wvb, wob);

  gemm3<<<768, 256, 0, stream>>>(
      qn, wqb, Qp, kb, wkb, Kp, vb, wvb, Vp, QSCALE);

  mask_flags<<<dim3(32, 32), 256, 0, stream>>>(mask, tflags);

  flash_attn<<<512, 512, 0, stream>>>(
      Qp, Kp, Vp, mask, tflags, P0, P1, l0, l1);

  combine_kernel<<<2048, 256, 0, stream>>>(P0, P1, l0, l1, AO);

  gemm_bm64<<<512, 256, 0, stream>>>(AO, wob, out, q);
}

// Round 19
// 121.770 us; speedup vs baseline: 1.1214x; 1.1214x over previous
//
#include <hip/hip_runtime.h>
#include <stdint.h>

typedef __attribute__((ext_vector_type(8))) short bf16x8;
typedef __attribute__((ext_vector_type(4))) short s16x4;
typedef __attribute__((ext_vector_type(4))) float f32x4;

__device__ __forceinline__ ushort f2bf(float f) {
  union { float f; uint32_t u; } c; c.f = f;
  uint32_t r = (c.u + 0x7fffu + ((c.u >> 16) & 1u)) >> 16;
  return (ushort)r;
}

__device__ __forceinline__ void gload16(const void* g, void* l) {
  __builtin_amdgcn_global_load_lds(
      (const __attribute__((address_space(1))) void*)g,
      (__attribute__((address_space(3))) void*)l, 16, 0, 0);
}

__device__ __forceinline__ unsigned lds_addr(const void* p) {
  return (unsigned)(uintptr_t)(__attribute__((address_space(3))) const char*)p;
}

__device__ __forceinline__ uint32_t cvtpk(float lo, float hi) {
  uint32_t d;
  asm("v_cvt_pk_bf16_f32 %0, %1, %2" : "=v"(d) : "v"(lo), "v"(hi));
  return d;
}

// ---------------- fused prep: LN(q) + cast k,v + cast 4 weights ----------------
__global__ __launch_bounds__(256) void prep_kernel(
    const float* __restrict__ q, const float* __restrict__ k,
    const float* __restrict__ v, const float* __restrict__ w_q,
    const float* __restrict__ w_k, const float* __restrict__ w_v,
    const float* __restrict__ w_o, const float* __restrict__ ln_g,
    const float* __restrict__ ln_b,
    ushort* __restrict__ qn, ushort* __restrict__ kb, ushort* __restrict__ vb,
    ushort* __restrict__ wqb, ushort* __restrict__ wkb,
    ushort* __restrict__ wvb, ushort* __restrict__ wob) {
  const int bid = blockIdx.x;
  const int t = threadIdx.x;
  if (bid < 4096) {
    const int row = bid;
    const float4 val = ((const float4*)(q + (size_t)row * 1024))[t];
    float s  = val.x + val.y + val.z + val.w;
    float s2 = val.x*val.x + val.y*val.y + val.z*val.z + val.w*val.w;
    #pragma unroll
    for (int off = 1; off < 64; off <<= 1) {
      s  += __shfl_xor(s,  off);
      s2 += __shfl_xor(s2, off);
    }
    __shared__ float red[8];
    const int wave = t >> 6, lane = t & 63;
    if (lane == 0) { red[wave*2] = s; red[wave*2+1] = s2; }
    __syncthreads();
    s  = red[0] + red[2] + red[4] + red[6];
    s2 = red[1] + red[3] + red[5] + red[7];
    const float mu = s * (1.0f/1024.0f);
    const float var = s2 * (1.0f/1024.0f) - mu*mu;
    const float rs = rsqrtf(var + 1e-6f);
    const float4 gg = ((const float4*)ln_g)[t];
    const float4 bb = ((const float4*)ln_b)[t];
    ushort4 o;
    o.x = f2bf((val.x - mu) * rs * gg.x + bb.x);
    o.y = f2bf((val.y - mu) * rs * gg.y + bb.y);
    o.z = f2bf((val.z - mu) * rs * gg.z + bb.z);
    o.w = f2bf((val.w - mu) * rs * gg.w + bb.w);
    ((ushort4*)(qn + (size_t)row * 1024))[t] = o;
    return;
  }
  const float* in; ushort* out; int i;
  if (bid < 12288) {
    const int idx = bid - 4096;
    const bool isv = idx >= 4096;
    in  = isv ? v : k;
    out = isv ? vb : kb;
    i = (idx & 4095) * 256 + t;
  } else {
    const int idx = bid - 12288;
    const int w = idx >> 10;
    in  = w == 0 ? w_q : (w == 1 ? w_k : (w == 2 ? w_v : w_o));
    out = w == 0 ? wqb : (w == 1 ? wkb : (w == 2 ? wvb : wob));
    i = (idx & 1023) * 256 + t;
  }
  const float4 val = ((const float4*)in)[i];
  ushort4 o;
  o.x = f2bf(val.x); o.y = f2bf(val.y); o.z = f2bf(val.z); o.w = f2bf(val.w);
  ((ushort4*)out)[i] = o;
}

// ---------------- mask tile flags (64x64 granularity) ----------------
__global__ __launch_bounds__(256) void mask_flags(
    const int* __restrict__ mask, int* __restrict__ flags) {
  const int qt = blockIdx.y, kt = blockIdx.x;
  const int t = threadIdx.x;
  const int* p = mask + (size_t)(qt * 64 + (t >> 2)) * 2048 + kt * 64 + (t & 3) * 16;
  int ok = 1;
  #pragma unroll
  for (int i = 0; i < 4; i++) {
    const int4 m = ((const int4*)p)[i];
    ok &= (m.x != 0) & (m.y != 0) & (m.z != 0) & (m.w != 0);
  }
  __shared__ int sok;
  if (t == 0) sok = 1;
  __syncthreads();
  if (!ok) atomicAnd(&sok, 0);
  __syncthreads();
  if (t == 0) flags[qt * 32 + kt] = sok;
}

// ---------------- QKV GEMM: 3 LDS buffers, unroll-by-3 static addressing -------
__global__ __launch_bounds__(256, 3) void gemm3(
    const ushort* __restrict__ A0, const ushort* __restrict__ W0, ushort* __restrict__ C0,
    const ushort* __restrict__ A1, const ushort* __restrict__ W1, ushort* __restrict__ C1,
    const ushort* __restrict__ A2, const ushort* __restrict__ W2, ushort* __restrict__ C2,
    float qscale) {
  __shared__ ushort As[3][4096];
  __shared__ ushort Bs[3][4096];
  const int t = threadIdx.x, lane = t & 63, wave = t >> 6;
  const int wr = wave >> 1, wc = wave & 1;
  const int lr = lane & 15, lg = lane >> 4;
  const int lin = blockIdx.x;
  const int swz = (lin & 7) * 96 + (lin >> 3);     // bijective: 768 = 8*96
  const int brow = ((swz >> 3) & 31) * 128, bcol = (swz & 7) * 128;
  const int z = swz >> 8;
  const ushort* A = z == 0 ? A0 : (z == 1 ? A1 : A2);
  const ushort* W = z == 0 ? W0 : (z == 1 ? W1 : W2);
  ushort*      C = z == 0 ? C0 : (z == 1 ? C1 : C2);
  const float sc = (z == 0) ? qscale : 1.0f;
  f32x4 acc[4][4] = {};
  const int r_ = t >> 2, cx = (t & 3) ^ ((r_ >> 1) & 3);   // source chunk XOR
  const ushort* gA  = A + (size_t)(brow + r_) * 1024 + cx * 8;
  const ushort* gB  = W + (size_t)(bcol + r_) * 1024 + cx * 8;
  const ushort* gA2 = gA + 64 * 1024;
  const ushort* gB2 = gB + 64 * 1024;
  const int woff = wave * 1024;                            // bytes
  char* const la0 = (char*)As[0] + woff;
  char* const la1 = (char*)As[1] + woff;
  char* const la2 = (char*)As[2] + woff;
  char* const lb0 = (char*)Bs[0] + woff;
  char* const lb1 = (char*)Bs[1] + woff;
  char* const lb2 = (char*)Bs[2] + woff;
  const int xA = ((lr >> 1) & 3) * 8;                      // read-side XOR (ushorts)

#define G_ISSUE_U(LA, LB, OFF) { \
    gload16(gA  + (OFF), (LA));        gload16(gA2 + (OFF), (LA) + 4096); \
    gload16(gB  + (OFF), (LB));        gload16(gB2 + (OFF), (LB) + 4096); }

#define G_COMPUTE_U(BI) { \
    const ushort* as_ = As[BI]; \
    const ushort* bs_ = Bs[BI]; \
    bf16x8 af[4], bfr[4]; \
    _Pragma("unroll") for (int i = 0; i < 4; i++) \
      af[i]  = *(const bf16x8*)&as_[(wr*64 + i*16 + lr) * 32 + ((lg*8) ^ xA)]; \
    _Pragma("unroll") for (int i = 0; i < 4; i++) \
      bfr[i] = *(const bf16x8*)&bs_[(wc*64 + i*16 + lr) * 32 + ((lg*8) ^ xA)]; \
    _Pragma("unroll") for (int mi = 0; mi < 4; mi++) \
      _Pragma("unroll") for (int ni = 0; ni < 4; ni++) \
        acc[mi][ni] = __builtin_amdgcn_mfma_f32_16x16x32_bf16(af[mi], bfr[ni], acc[mi][ni], 0, 0, 0); }

  G_ISSUE_U(la0, lb0, 0);
  G_ISSUE_U(la1, lb1, 32);
  for (int k = 0; k < 10; ++k) {
    asm volatile("s_waitcnt vmcnt(4)" ::: "memory");
    __builtin_amdgcn_s_barrier();
    G_ISSUE_U(la2, lb2, 64);
    G_COMPUTE_U(0);
    asm volatile("s_waitcnt vmcnt(4)" ::: "memory");
    __builtin_amdgcn_s_barrier();
    G_ISSUE_U(la0, lb0, 96);
    G_COMPUTE_U(1);
    asm volatile("s_waitcnt vmcnt(4)" ::: "memory");
    __builtin_amdgcn_s_barrier();
    G_ISSUE_U(la1, lb1, 128);
    G_COMPUTE_U(2);
    gA += 96; gA2 += 96; gB += 96; gB2 += 96;
  }
  asm volatile("s_waitcnt vmcnt(4)" ::: "memory");
  __builtin_amdgcn_s_barrier();
  G_COMPUTE_U(0);
  asm volatile("s_waitcnt vmcnt(0)" ::: "memory");
  __builtin_amdgcn_s_barrier();
  G_COMPUTE_U(1);
#undef G_ISSUE_U
#undef G_COMPUTE_U

  #pragma unroll
  for (int mi = 0; mi < 4; mi++) {
    #pragma unroll
    for (int ni = 0; ni < 4; ni++) {
      #pragma unroll
      for (int r = 0; r < 4; r++) {
        const size_t row = brow + wr*64 + mi*16 + lg*4 + r;
        const size_t col = bcol + wc*64 + ni*16 + lr;
        C[row * 1024 + col] = f2bf(acc[mi][ni][r] * sc);
      }
    }
  }
}

// ---------------- Final GEMM: BM=64, XCD+T2 swizzles, fused residual -----------
__global__ __launch_bounds__(256) void gemm_bm64(
    const ushort* __restrict__ A, const ushort* __restrict__ W,
    float* __restrict__ Cf, const float* __restrict__ resid) {
  __shared__ ushort As[4][2048];
  __shared__ ushort Bs[4][4096];
  const int t = threadIdx.x, lane = t & 63, wave = t >> 6;
  const int wr = wave >> 1, wc = wave & 1;
  const int lr = lane & 15, lg = lane >> 4;
  const int lin = blockIdx.x;
  const int swz = (lin & 7) * 64 + (lin >> 3);     // bijective: 512 = 8*64
  const int brow = (swz >> 3) * 64, bcol = (swz & 7) * 128;
  f32x4 acc[2][4] = {};
  const int r_ = t >> 2, cx = (t & 3) ^ ((r_ >> 1) & 3);
  const ushort* gA = A + (size_t)(brow + r_) * 1024 + cx * 8;
  const ushort* gB = W + (size_t)(bcol + r_) * 1024 + cx * 8;
  const int woff = wave * 1024;
  const int xA = ((lr >> 1) & 3) * 8;

#define G_ISSUE(S) { \
    char* la = (char*)As + ((S) & 3) * 4096 + woff; \
    char* lb = (char*)Bs + ((S) & 3) * 8192 + woff; \
    const ushort* ap_ = gA + (S) * 32; \
    const ushort* bp_ = gB + (S) * 32; \
    gload16(ap_, la); \
    gload16(bp_, lb); gload16(bp_ + 64 * 1024, lb + 4096); }

#define G_COMPUTE(S) { \
    const ushort* as_ = As[(S) & 3]; \
    const ushort* bs_ = Bs[(S) & 3]; \
    bf16x8 af[2], bfr[4]; \
    _Pragma("unroll") for (int i = 0; i < 2; i++) \
      af[i]  = *(const bf16x8*)&as_[(wr*32 + i*16 + lr) * 32 + ((lg*8) ^ xA)]; \
    _Pragma("unroll") for (int i = 0; i < 4; i++) \
      bfr[i] = *(const bf16x8*)&bs_[(wc*64 + i*16 + lr) * 32 + ((lg*8) ^ xA)]; \
    _Pragma("unroll") for (int mi = 0; mi < 2; mi++) \
      _Pragma("unroll") for (int ni = 0; ni < 4; ni++) \
        acc[mi][ni] = __builtin_amdgcn_mfma_f32_16x16x32_bf16(af[mi], bfr[ni], acc[mi][ni], 0, 0, 0); }

  G_ISSUE(0); G_ISSUE(1); G_ISSUE(2);
  for (int s = 0; s < 30; ++s) {
    asm volatile("s_waitcnt vmcnt(6)" ::: "memory");
    __builtin_amdgcn_s_barrier();
    if (s < 29) G_ISSUE(s + 3);
    G_COMPUTE(s);
  }
  asm volatile("s_waitcnt vmcnt(3)" ::: "memory");
  __builtin_amdgcn_s_barrier();
  G_COMPUTE(30);
  asm volatile("s_waitcnt vmcnt(0)" ::: "memory");
  __builtin_amdgcn_s_barrier();
  G_COMPUTE(31);
#undef G_ISSUE
#undef G_COMPUTE

  #pragma unroll
  for (int mi = 0; mi < 2; mi++) {
    #pragma unroll
    for (int ni = 0; ni < 4; ni++) {
      #pragma unroll
      for (int r = 0; r < 4; r++) {
        const size_t row = brow + wr*32 + mi*16 + lg*4 + r;
        const size_t col = bcol + wc*64 + ni*16 + lr;
        Cf[row * 1024 + col] = acc[mi][ni][r] + resid[row * 1024 + col];
      }
    }
  }
}

// ---------------- Flash attention: 32q/wave (2 q-tiles), 8-wave blocks ---------
// 512 thr/block, 256 blocks (1/CU). K-frags and V tr-reads loaded ONCE per wave
// feed BOTH q-tiles -> per-q LDS traffic halved vs 16q/wave (R16).
// Swapped QK^T, m=0 softmax, l via MFMA(P,1); proven R16 staging/repack.
__global__ __launch_bounds__(512) void flash_attn(
    const ushort* __restrict__ Qp, const ushort* __restrict__ Kp,
    const ushort* __restrict__ Vp, const int* __restrict__ mask,
    const int* __restrict__ tflags, ushort* __restrict__ AO) {
  const int L = 2048;
  const int lin = blockIdx.x;
  const int swzb = (lin & 7) * 32 + (lin >> 3);    // bijective: 256 = 8*32
  const int qb = swzb & 7, h = (swzb >> 3) & 15, b = swzb >> 7;
  const int t = threadIdx.x, lane = t & 63, wave = t >> 6;   // wave 0..7
  const int l15 = lane & 15, hg = lane >> 4;                 // hg 0..3
  __shared__ ushort Ks[2][8192];   // pair buffer: 2 tiles x 8KB (64kv x 64d)
  __shared__ ushort Vs[2][8192];
  const size_t base = (size_t)b * L * 1024 + h * 64;
  const int qw0 = qb * 256 + wave * 32;            // this wave's 32 q-rows

  // Q B-frags: qf[qt][kc], lane holds q-col = l15, d = kc*32 + hg*8 + j
  bf16x8 qf[2][2];
  #pragma unroll
  for (int qt = 0; qt < 2; qt++)
    #pragma unroll
    for (int kc = 0; kc < 2; kc++)
      qf[qt][kc] = *(const bf16x8*)(Qp + base +
                     (size_t)(qw0 + qt*16 + l15) * 1024 + kc*32 + hg*8);

  f32x4 accO[2][4] = {};           // [qt][dblk]
  f32x4 accL[2] = {};
  const bf16x8 onef = {16256, 16256, 16256, 16256, 16256, 16256, 16256, 16256};

  // K staging (512 thr): row r5 = t>>3, source chunk (t&7)^(r5&7) -> XOR-swizzled
  const int r5 = t >> 3;
  const ushort* gK = Kp + base + (size_t)r5 * 1024 + ((t & 7) ^ (r5 & 7)) * 8;
  // V staging: subtile order
  const int vkv = (t >> 5) * 4 + ((t & 7) >> 1);
  const int vd  = ((t >> 3) & 3) * 16 + (t & 1) * 8;
  const ushort* gV = Vp + base + (size_t)vkv * 1024 + vd;

  const unsigned vbase = lds_addr((const char*)Vs) + hg * 1024 + l15 * 8;

#define STAGE2(P, BUF) { \
    char* kb_ = (char*)Ks[BUF] + wave * 1024; \
    const ushort* gk_ = gK + (size_t)(2*(P)) * 65536; \
    gload16(gk_, kb_);           gload16(gk_ + 65536, kb_ + 8192); \
    char* vb_ = (char*)Vs[BUF] + wave * 1024; \
    const ushort* gv_ = gV + (size_t)(2*(P)) * 65536; \
    gload16(gv_, vb_);           gload16(gv_ + 65536, vb_ + 8192); }

#define TRREAD(VLO, VHI, VA, C) { \
    _Pragma("unroll") for (int dblk = 0; dblk < 4; dblk++) \
      asm volatile("ds_read_b64_tr_b16 %0, %2 offset:%3\n\t" \
                   "ds_read_b64_tr_b16 %1, %2 offset:%4" \
                   : "=v"(VLO[dblk]), "=v"(VHI[dblk]) \
                   : "v"(VA), "i"((C)*4096 + dblk*128), "i"((C)*4096 + dblk*128 + 512) \
                   : "memory"); }

  STAGE2(0, 0);
  const int flagBase = (qb * 4 + (wave >> 1)) * 32;

  for (int p = 0; p < 16; ++p) {
    asm volatile("s_waitcnt vmcnt(0)" ::: "memory");
    __builtin_amdgcn_s_barrier();
    if (p + 1 < 16) { STAGE2(p + 1, (p + 1) & 1); }

    #pragma unroll
    for (int half = 0; half < 2; ++half) {
      const int kvt = 2*p + half;
      const char* KsB = (const char*)Ks[p & 1] + half * 8192;
      const unsigned va = vbase + (p & 1) * 16384 + half * 8192;

      // ---- S^T = K Q^T : K-frags read ONCE, feed both q-tiles
      f32x4 s[2][4] = {};
      const int rx16 = (l15 & 7) << 4;
      __builtin_amdgcn_s_setprio(1);
      #pragma unroll
      for (int kc = 0; kc < 2; kc++) {
        const int cb = (kc*64 + hg*16) ^ rx16;
        const bf16x8 k0 = *(const bf16x8*)(KsB + (     l15) * 128 + cb);
        const bf16x8 k1 = *(const bf16x8*)(KsB + (16 + l15) * 128 + cb);
        const bf16x8 k2 = *(const bf16x8*)(KsB + (32 + l15) * 128 + cb);
        const bf16x8 k3 = *(const bf16x8*)(KsB + (48 + l15) * 128 + cb);
        #pragma unroll
        for (int qt = 0; qt < 2; qt++) {
          s[qt][0] = __builtin_amdgcn_mfma_f32_16x16x32_bf16(k0, qf[qt][kc], s[qt][0], 0, 0, 0);
          s[qt][1] = __builtin_amdgcn_mfma_f32_16x16x32_bf16(k1, qf[qt][kc], s[qt][1], 0, 0, 0);
          s[qt][2] = __builtin_amdgcn_mfma_f32_16x16x32_bf16(k2, qf[qt][kc], s[qt][2], 0, 0, 0);
          s[qt][3] = __builtin_amdgcn_mfma_f32_16x16x32_bf16(k3, qf[qt][kc], s[qt][3], 0, 0, 0);
        }
      }
      __builtin_amdgcn_s_setprio(0);

      // ---- tr-reads chunk 0 (kv 0-31 of this tile)
      s16x4 vlo[4], vhi[4];
      TRREAD(vlo, vhi, va, 0);

      // ---- mask (rare path): lane holds q = qt*16+l15, kv = tile*16 + hg*4 + r
      if (tflags[flagBase + kvt] == 0) {
        #pragma unroll
        for (int qt = 0; qt < 2; qt++) {
          const size_t mrow = (size_t)(qw0 + qt*16 + l15) * L + kvt * 64;
          #pragma unroll
          for (int r = 0; r < 4; ++r) {
            const int kvr = hg*4 + r;
            if (mask[mrow + kvr] == 0)      s[qt][0][r] = -1e9f;
            if (mask[mrow + 16 + kvr] == 0) s[qt][1][r] = -1e9f;
            if (mask[mrow + 32 + kvr] == 0) s[qt][2][r] = -1e9f;
            if (mask[mrow + 48 + kvr] == 0) s[qt][3][r] = -1e9f;
          }
        }
      }

      // ---- p = exp2(s)  (m=0: Q pre-scaled, scores O(1))
      #pragma unroll
      for (int qt = 0; qt < 2; qt++)
        #pragma unroll
        for (int ni = 0; ni < 4; ++ni)
          #pragma unroll
          for (int r = 0; r < 4; ++r)
            s[qt][ni][r] = __builtin_amdgcn_exp2f(s[qt][ni][r]);

      // ---- repack P into A-frags (per qt, per 32-kv chunk): cvtpk + P32 + P16
      union U8 { uint32_t u[4]; bf16x8 v; };
      bf16x8 pa[2][2];
      #pragma unroll
      for (int qt = 0; qt < 2; qt++) {
        #pragma unroll
        for (int c = 0; c < 2; ++c) {
          const f32x4& ta = s[qt][2*c];
          const f32x4& tb = s[qt][2*c + 1];
          uint32_t A = cvtpk(ta[0], ta[1]), B = cvtpk(ta[2], ta[3]);
          uint32_t C = cvtpk(tb[0], tb[1]), D = cvtpk(tb[2], tb[3]);
          asm("v_permlane32_swap_b32 %0, %1" : "+v"(A), "+v"(C));
          asm("v_permlane16_swap_b32 %0, %1" : "+v"(A), "+v"(C));
          asm("v_permlane32_swap_b32 %0, %1" : "+v"(B), "+v"(D));
          asm("v_permlane16_swap_b32 %0, %1" : "+v"(B), "+v"(D));
          U8 f; f.u[0] = A; f.u[1] = B; f.u[2] = C; f.u[3] = D;
          pa[qt][c] = f.v;
        }
      }

      // ---- PV chunk 0 + l  (V frags shared by both q-tiles)
      asm volatile("s_waitcnt lgkmcnt(0)" ::: "memory");
      __builtin_amdgcn_sched_barrier(0);
      __builtin_amdgcn_s_setprio(1);
      #pragma unroll
      for (int dblk = 0; dblk < 4; dblk++) {
        const bf16x8 bv = __builtin_shufflevector(vlo[dblk], vhi[dblk],
                                                  0, 1, 2, 3, 4, 5, 6, 7);
        accO[0][dblk] = __builtin_amdgcn_mfma_f32_16x16x32_bf16(pa[0][0], bv, accO[0][dblk], 0, 0, 0);
        accO[1][dblk] = __builtin_amdgcn_mfma_f32_16x16x32_bf16(pa[1][0], bv, accO[1][dblk], 0, 0, 0);
      }
      accL[0] = __builtin_amdgcn_mfma_f32_16x16x32_bf16(pa[0][0], onef, accL[0], 0, 0, 0);
      accL[1] = __builtin_amdgcn_mfma_f32_16x16x32_bf16(pa[1][0], onef, accL[1], 0, 0, 0);
      __builtin_amdgcn_s_setprio(0);

      // ---- tr-reads chunk 1, PV chunk 1 + l
      TRREAD(vlo, vhi, va, 1);
      asm volatile("s_waitcnt lgkmcnt(0)" ::: "memory");
      __builtin_amdgcn_sched_barrier(0);
      __builtin_amdgcn_s_setprio(1);
      #pragma unroll
      for (int dblk = 0; dblk < 4; dblk++) {
        const bf16x8 bv = __builtin_shufflevector(vlo[dblk], vhi[dblk],
                                                  0, 1, 2, 3, 4, 5, 6, 7);
        accO[0][dblk] = __builtin_amdgcn_mfma_f32_16x16x32_bf16(pa[0][1], bv, accO[0][dblk], 0, 0, 0);
        accO[1][dblk] = __builtin_amdgcn_mfma_f32_16x16x32_bf16(pa[1][1], bv, accO[1][dblk], 0, 0, 0);
      }
      accL[0] = __builtin_amdgcn_mfma_f32_16x16x32_bf16(pa[0][1], onef, accL[0], 0, 0, 0);
      accL[1] = __builtin_amdgcn_mfma_f32_16x16x32_bf16(pa[1][1], onef, accL[1], 0, 0, 0);
      __builtin_amdgcn_s_setprio(0);
    }
  }

  // ---- epilogue: accO[qt] lane holds d-col = l15, q = qw0 + qt*16 + hg*4 + r
  #pragma unroll
  for (int qt = 0; qt < 2; qt++) {
    #pragma unroll
    for (int r = 0; r < 4; ++r) {
      const float inv = 1.0f / accL[qt][r];
      const size_t row = (size_t)b * L + qw0 + qt*16 + hg*4 + r;
      #pragma unroll
      for (int dblk = 0; dblk < 4; dblk++)
        AO[row * 1024 + h*64 + dblk*16 + l15] = f2bf(accO[qt][dblk][r] * inv);
    }
  }
#undef STAGE2
#undef TRREAD
}

extern "C" void kernel_launch(void* const* d_in, const int* in_sizes, int n_in,
                              void* d_out, int out_size, void* d_ws, size_t ws_size,
                              hipStream_t stream) {
  const float* q    = (const float*)d_in[0];
  const float* k    = (const float*)d_in[1];
  const float* v    = (const float*)d_in[2];
  const int*   mask = (const int*)d_in[3];
  const float* w_q  = (const float*)d_in[4];
  const float* w_k  = (const float*)d_in[5];
  const float* w_v  = (const float*)d_in[6];
  const float* w_o  = (const float*)d_in[7];
  const float* ln_g = (const float*)d_in[8];
  const float* ln_b = (const float*)d_in[9];
  float* out = (float*)d_out;

  char* ws = (char*)d_ws;
  const size_t MB = (size_t)1 << 20;
  ushort* qn  = (ushort*)(ws + 0*MB);
  ushort* kb  = (ushort*)(ws + 8*MB);    // dead after QKV GEMM; tflags reuses it
  ushort* vb  = (ushort*)(ws + 16*MB);
  ushort* wqb = (ushort*)(ws + 24*MB);
  ushort* wkb = (ushort*)(ws + 26*MB);
  ushort* wvb = (ushort*)(ws + 28*MB);
  ushort* wob = (ushort*)(ws + 30*MB);
  ushort* Qp  = (ushort*)(ws + 32*MB);
  ushort* Kp  = (ushort*)(ws + 40*MB);
  ushort* Vp  = (ushort*)(ws + 48*MB);
  ushort* AO  = (ushort*)(ws + 56*MB);
  int* tflags = (int*)(ws + 8*MB);       // written after gemm3 consumed kb

  const float QSCALE = 0.125f * 1.44269504089f;   // 1/sqrt(64) * log2(e)

  prep_kernel<<<16384, 256, 0, stream>>>(
      q, k, v, w_q, w_k, w_v, w_o, ln_g, ln_b,
      qn, kb, vb, wqb, wkb, wvb, wob);

  gemm3<<<768, 256, 0, stream>>>(
      qn, wqb, Qp, kb, wkb, Kp, vb, wvb, Vp, QSCALE);

  mask_flags<<<dim3(32, 32), 256, 0, stream>>>(mask, tflags);

  flash_attn<<<256, 512, 0, stream>>>(Qp, Kp, Vp, mask, tflags, AO);

  gemm_bm64<<<512, 256, 0, stream>>>(AO, wob, out, q);
}